// Round 5
// baseline (117.502 us; speedup 1.0000x reference)
//
#include <hip/hip_runtime.h>
#include <hip/hip_bf16.h>

#define VOCAB 50000
#define HID   256
#define BATCH 512
#define GH    768   // 3*H

typedef __attribute__((ext_vector_type(8))) __bf16 bf16x8;
typedef __attribute__((ext_vector_type(4))) float f32x4;
typedef __attribute__((ext_vector_type(4))) unsigned int u32x4;

union BFrag {
    bf16x8 v;
    u32x4  q;
    unsigned short u[8];
};

__device__ __forceinline__ unsigned short f2bf(float f) {
    unsigned int x = __builtin_bit_cast(unsigned int, f);
    x += 0x7FFFu + ((x >> 16) & 1u);          // round-to-nearest-even
    return (unsigned short)(x >> 16);
}

__device__ __forceinline__ float fast_sigmoid(float x) {
    return 1.0f / (1.0f + __expf(-x));
}
__device__ __forceinline__ float fast_tanh(float x) {
    return 1.0f - 2.0f / (1.0f + __expf(2.0f * x));
}

__device__ __forceinline__ void cvt8(BFrag& t, f32x4 lo, f32x4 hi) {
    t.u[0] = f2bf(lo.x); t.u[1] = f2bf(lo.y);
    t.u[2] = f2bf(lo.z); t.u[3] = f2bf(lo.w);
    t.u[4] = f2bf(hi.x); t.u[5] = f2bf(hi.y);
    t.u[6] = f2bf(hi.z); t.u[7] = f2bf(hi.w);
}

// ---------------------------------------------------------------------------
// Fragment-ordered A layout: A_frag[mt][kk][g][r], each entry = 16B (8 bf16).
//   row = mt*16 + r (mt = row/16, r = row%16)
//   k   = kk*32 + g*8 + e (e = 0..7 within the 16B fragment)
// Flat fragment index: ((mt*8 + kk)*4 + g)*16 + r  = (mt*8+kk)*64 + (g*16+r)
// With lane = g*16+r, a wave's fragment load is base + lane*16B -> 1KB
// contiguous, perfectly coalesced. A stays L2-resident (256 KB).
// ---------------------------------------------------------------------------

// K0: repack f32 [M][256] row-major -> fragment-ordered bf16. One frag/thread.
__global__ __launch_bounds__(256) void repack_f32(
    const float* __restrict__ src, u32x4* __restrict__ dst, int nFrag)
{
    int fid = blockIdx.x * 256 + threadIdx.x;
    if (fid >= nFrag) return;
    int r = fid & 15, g = (fid >> 4) & 3, kk = (fid >> 6) & 7, mt = fid >> 9;
    const f32x4* p = reinterpret_cast<const f32x4*>(
        src + (size_t)(mt * 16 + r) * 256 + kk * 32 + g * 8);
    BFrag t; cvt8(t, p[0], p[1]);
    dst[fid] = t.q;
}

// GEMM: C[M x Ncols] = A @ B^T, A fragment-ordered bf16, B [Ncols][256] f32.
// No LDS, no barriers. Block = 4 waves x 32 cols = 128 cols. B-row fragments
// (2 cols/lane x 8 k-steps) converted once and held in registers; A fragments
// streamed coalesced from L2; 64 MFMA per 32 A-loads per chunk.
// EPI 0: raw f32 store    1: tanh(acc + bias[col])
template <int EPI>
__global__ __launch_bounds__(256) void gemm_frag(
    const u32x4* __restrict__ Af, const float* __restrict__ Bm,
    float* __restrict__ C, const float* __restrict__ bias,
    int Ncols, int mChunks)
{
    const int tid  = threadIdx.x;
    const int wid  = tid >> 6;
    const int lane = tid & 63;
    const int r    = lane & 15;
    const int g    = lane >> 4;
    const int colbase = blockIdx.x * 128 + wid * 32;

    // ---- B fragments: 2 cols x 8 k-steps, load once, keep in registers ----
    BFrag bf0[8], bf1[8];
    float biasv[2] = {0.f, 0.f};
    #pragma unroll
    for (int n = 0; n < 2; n++) {
        int col  = colbase + n * 16 + r;
        int bcol = col < Ncols ? col : (Ncols - 1);
        const f32x4* wrow = reinterpret_cast<const f32x4*>(Bm + (size_t)bcol * 256);
        #pragma unroll
        for (int kk = 0; kk < 8; kk++) {
            f32x4 lo = __builtin_nontemporal_load(&wrow[kk * 8 + g * 2]);
            f32x4 hi = __builtin_nontemporal_load(&wrow[kk * 8 + g * 2 + 1]);
            if (n == 0) cvt8(bf0[kk], lo, hi);
            else        cvt8(bf1[kk], lo, hi);
        }
        if (EPI == 1) biasv[n] = bias[bcol];
    }

    for (int c = 0; c < mChunks; c++) {
        const int mt0 = (blockIdx.y * mChunks + c) * 4;   // 4 mt-groups = 64 rows
        const u32x4* abase = Af + (size_t)mt0 * 8 * 64 + lane;

        f32x4 acc[4][2];
        #pragma unroll
        for (int m = 0; m < 4; m++) {
            acc[m][0] = (f32x4){0.f, 0.f, 0.f, 0.f};
            acc[m][1] = (f32x4){0.f, 0.f, 0.f, 0.f};
        }

        #pragma unroll
        for (int kk = 0; kk < 8; kk++) {
            #pragma unroll
            for (int m = 0; m < 4; m++) {
                BFrag a;
                a.q = abase[(m * 8 + kk) * 64];
                acc[m][0] = __builtin_amdgcn_mfma_f32_16x16x32_bf16(a.v, bf0[kk].v, acc[m][0], 0, 0, 0);
                acc[m][1] = __builtin_amdgcn_mfma_f32_16x16x32_bf16(a.v, bf1[kk].v, acc[m][1], 0, 0, 0);
            }
        }

        const int rowbase = (blockIdx.y * mChunks + c) * 64 + g * 4;
        #pragma unroll
        for (int m = 0; m < 4; m++) {
            #pragma unroll
            for (int n = 0; n < 2; n++) {
                int col = colbase + n * 16 + r;
                if (col < Ncols) {
                    #pragma unroll
                    for (int j = 0; j < 4; j++) {
                        float v = acc[m][n][j];
                        if (EPI == 1) v = fast_tanh(v + biasv[n]);
                        C[(size_t)(rowbase + m * 16 + j) * Ncols + col] = v;
                    }
                }
            }
        }
    }
}

// K2: GRU gates. One block per batch row, thread = k. Writes h1 (f32, d_out
// tail) and h1 in fragment-ordered bf16 (for K3's A operand).
__global__ __launch_bounds__(256) void gru_gate(
    const int* __restrict__ inp, const float* __restrict__ hidden,
    const float* __restrict__ w_ih, const float* __restrict__ b_ih,
    const float* __restrict__ b_hh, const float* __restrict__ hproj,
    float* __restrict__ h1out, unsigned short* __restrict__ h1frag)
{
    const int b = blockIdx.x;
    const int k = threadIdx.x;
    const int c = inp[b];

    float xr = w_ih[(size_t)k * VOCAB + c]         + b_ih[k];
    float xz = w_ih[(size_t)(k + 256) * VOCAB + c] + b_ih[k + 256];
    float xn = w_ih[(size_t)(k + 512) * VOCAB + c] + b_ih[k + 512];

    float hr = hproj[b * GH + k]       + b_hh[k];
    float hz = hproj[b * GH + 256 + k] + b_hh[k + 256];
    float hn = hproj[b * GH + 512 + k] + b_hh[k + 512];

    float rg = fast_sigmoid(xr + hr);
    float zg = fast_sigmoid(xz + hz);
    float ng = fast_tanh(xn + rg * hn);
    float h0 = hidden[b * HID + k];
    float h1 = (1.0f - zg) * ng + zg * h0;

    h1out[b * HID + k] = h1;

    // fragment-ordered bf16 write
    int mt = b >> 4, rr = b & 15;
    int kk = k >> 5, gg = (k >> 3) & 3, e = k & 7;
    size_t fid = (size_t)((mt * 8 + kk) * 4 + gg) * 16 + rr;
    h1frag[fid * 8 + e] = f2bf(h1);
}

extern "C" void kernel_launch(void* const* d_in, const int* in_sizes, int n_in,
                              void* d_out, int out_size, void* d_ws, size_t ws_size,
                              hipStream_t stream) {
    const int*   input  = (const int*)  d_in[0];
    // d_in[1] = target (unused)
    const float* hidden = (const float*)d_in[2];
    const float* w_ih   = (const float*)d_in[3];
    const float* w_hh   = (const float*)d_in[4];
    const float* b_ih   = (const float*)d_in[5];
    const float* b_hh   = (const float*)d_in[6];
    const float* w_out  = (const float*)d_in[7];
    const float* b_out  = (const float*)d_in[8];

    float* logit = (float*)d_out;                            // [512, 50000]
    float* h1    = (float*)d_out + (size_t)BATCH * VOCAB;    // [512, 256]

    u32x4* hfrag  = (u32x4*)d_ws;                                  // 256 KB
    u32x4* h1frag = (u32x4*)((char*)d_ws + 256 * 1024);            // 256 KB
    float* hproj  = (float*)((char*)d_ws + 512 * 1024);           // 1.5 MB

    const int nFrag = BATCH * HID / 8;   // 16384

    // K0: hidden -> fragment-ordered bf16
    repack_f32<<<nFrag / 256, 256, 0, stream>>>(hidden, hfrag, nFrag);

    // K1: hproj = h0 @ w_hh^T   (512 x 768, K=256)
    dim3 g1(GH / 128, BATCH / 64);          // (6, 8), mChunks = 1
    gemm_frag<0><<<g1, 256, 0, stream>>>(hfrag, w_hh, hproj, nullptr, GH, 1);

    // K2: gates -> h1 (f32) + h1frag (fragment-ordered bf16)
    gru_gate<<<BATCH, 256, 0, stream>>>(input, hidden, w_ih, b_ih, b_hh, hproj,
                                        h1, (unsigned short*)h1frag);

    // K3: logit = tanh(h1 @ w_out^T + b_out)   (512 x 50000, K=256)
    dim3 g3((VOCAB + 127) / 128, 1);        // 391 blocks, mChunks = 8
    gemm_frag<1><<<g3, 256, 0, stream>>>(h1frag, w_out, logit, b_out, VOCAB, 8);
}

// Round 6
// 73.662 us; speedup vs baseline: 1.5951x; 1.5951x over previous
//
#include <hip/hip_runtime.h>
#include <hip/hip_bf16.h>

#define VOCAB 50000
#define HID   256
#define BATCH 512
#define GH    768   // 3*H

typedef __attribute__((ext_vector_type(8))) __bf16 bf16x8;
typedef __attribute__((ext_vector_type(4))) float f32x4;
typedef __attribute__((ext_vector_type(4))) unsigned int u32x4;

union BFrag {
    bf16x8 v;
    u32x4  q;
    unsigned short u[8];
};

__device__ __forceinline__ unsigned short f2bf(float f) {
    unsigned int x = __builtin_bit_cast(unsigned int, f);
    x += 0x7FFFu + ((x >> 16) & 1u);          // round-to-nearest-even
    return (unsigned short)(x >> 16);
}

__device__ __forceinline__ float fast_sigmoid(float x) {
    return 1.0f / (1.0f + __expf(-x));
}
__device__ __forceinline__ float fast_tanh(float x) {
    return 1.0f - 2.0f / (1.0f + __expf(2.0f * x));
}

__device__ __forceinline__ void cvt8(BFrag& t, f32x4 lo, f32x4 hi) {
    t.u[0] = f2bf(lo.x); t.u[1] = f2bf(lo.y);
    t.u[2] = f2bf(lo.z); t.u[3] = f2bf(lo.w);
    t.u[4] = f2bf(hi.x); t.u[5] = f2bf(hi.y);
    t.u[6] = f2bf(hi.z); t.u[7] = f2bf(hi.w);
}

// ---------------------------------------------------------------------------
// Fragment-ordered A layout: A_frag[mt][kk][g][r], each entry = 16B (8 bf16).
//   row = mt*16 + r ; k = kk*32 + g*8 + e
// Flat fid = (mt*8 + kk)*64 + (g*16 + r); wave load = base + lane*16B (1KB).
// ---------------------------------------------------------------------------

// K0: repack f32 [M][256] row-major -> fragment-ordered bf16. One frag/thread.
__global__ __launch_bounds__(256) void repack_f32(
    const float* __restrict__ src, u32x4* __restrict__ dst, int nFrag)
{
    int fid = blockIdx.x * 256 + threadIdx.x;
    if (fid >= nFrag) return;
    int r = fid & 15, g = (fid >> 4) & 3, kk = (fid >> 6) & 7, mt = fid >> 9;
    const f32x4* p = reinterpret_cast<const f32x4*>(
        src + (size_t)(mt * 16 + r) * 256 + kk * 32 + g * 8);
    BFrag t; cvt8(t, p[0], p[1]);
    dst[fid] = t.q;
}

// GEMM: C = A @ B^T. A fragment-ordered bf16 (L2-resident), B [Ncols][256] f32.
// No LDS, no barriers. Block = 256 thr = 4 waves arranged 2x2; each wave owns
// 32 rows x 32 cols per chunk. B-fragments (16 = 64 VGPR) pinned in registers
// for the whole kernel (launch_bounds(256,2) budget + asm tie). Per chunk a
// wave loads only its 16KB slice of A, coalesced (16 x 1KB wave-loads).
// EPI 0: raw f32 store    1: tanh(acc + bias[col])
template <int EPI>
__global__ __launch_bounds__(256, 2) void gemm_ms(
    const u32x4* __restrict__ Af, const float* __restrict__ Bm,
    float* __restrict__ C, const float* __restrict__ bias,
    int Ncols, int mChunks)
{
    const int tid  = threadIdx.x;
    const int wid  = tid >> 6;
    const int wr   = wid >> 1;                // row-half of 64-row chunk
    const int wc   = wid & 1;                 // col-half of 64-col block
    const int lane = tid & 63;
    const int r    = lane & 15;
    const int g    = lane >> 4;
    const int colbase = blockIdx.x * 64 + wc * 32;

    // ---- B fragments: 2 col-groups x 8 k-steps, convert once, pin in regs ----
    BFrag bf[2][8];
    float biasv[2] = {0.f, 0.f};
    #pragma unroll
    for (int n = 0; n < 2; n++) {
        int col  = colbase + n * 16 + r;
        int bcol = col < Ncols ? col : (Ncols - 1);
        const f32x4* wrow = reinterpret_cast<const f32x4*>(Bm + (size_t)bcol * 256);
        #pragma unroll
        for (int kk = 0; kk < 8; kk++)
            cvt8(bf[n][kk], wrow[kk * 8 + g * 2], wrow[kk * 8 + g * 2 + 1]);
        if (EPI == 1) biasv[n] = bias[bcol];
    }
    #pragma unroll
    for (int n = 0; n < 2; n++)
        #pragma unroll
        for (int kk = 0; kk < 8; kk++)
            asm volatile("" : "+v"(bf[n][kk].q));   // pin: forbid re-load

    for (int c = 0; c < mChunks; c++) {
        const int chunk = blockIdx.y * mChunks + c;
        const int mt0   = chunk * 4 + wr * 2;       // this wave's 2 mt-groups
        const u32x4* a0 = Af + (size_t)mt0 * 8 * 64 + lane;

        f32x4 acc[2][2];
        #pragma unroll
        for (int m = 0; m < 2; m++) {
            acc[m][0] = (f32x4){0.f, 0.f, 0.f, 0.f};
            acc[m][1] = (f32x4){0.f, 0.f, 0.f, 0.f};
        }

        #pragma unroll
        for (int kk = 0; kk < 8; kk++) {
            BFrag a0f, a1f;
            a0f.q = a0[kk * 64];                    // mt0,   coalesced 1KB
            a1f.q = a0[(8 + kk) * 64];              // mt0+1, coalesced 1KB
            acc[0][0] = __builtin_amdgcn_mfma_f32_16x16x32_bf16(a0f.v, bf[0][kk].v, acc[0][0], 0, 0, 0);
            acc[0][1] = __builtin_amdgcn_mfma_f32_16x16x32_bf16(a0f.v, bf[1][kk].v, acc[0][1], 0, 0, 0);
            acc[1][0] = __builtin_amdgcn_mfma_f32_16x16x32_bf16(a1f.v, bf[0][kk].v, acc[1][0], 0, 0, 0);
            acc[1][1] = __builtin_amdgcn_mfma_f32_16x16x32_bf16(a1f.v, bf[1][kk].v, acc[1][1], 0, 0, 0);
        }

        const int rowbase = chunk * 64 + wr * 32 + g * 4;
        #pragma unroll
        for (int m = 0; m < 2; m++) {
            #pragma unroll
            for (int n = 0; n < 2; n++) {
                int col = colbase + n * 16 + r;
                if (col < Ncols) {
                    #pragma unroll
                    for (int j = 0; j < 4; j++) {
                        float v = acc[m][n][j];
                        if (EPI == 1) v = fast_tanh(v + biasv[n]);
                        C[(size_t)(rowbase + m * 16 + j) * Ncols + col] = v;
                    }
                }
            }
        }
    }
}

// K2: GRU gates. One block per batch row, thread = k. Writes h1 (f32, d_out
// tail) and h1 in fragment-ordered bf16 (for K3's A operand).
__global__ __launch_bounds__(256) void gru_gate(
    const int* __restrict__ inp, const float* __restrict__ hidden,
    const float* __restrict__ w_ih, const float* __restrict__ b_ih,
    const float* __restrict__ b_hh, const float* __restrict__ hproj,
    float* __restrict__ h1out, unsigned short* __restrict__ h1frag)
{
    const int b = blockIdx.x;
    const int k = threadIdx.x;
    const int c = inp[b];

    float xr = w_ih[(size_t)k * VOCAB + c]         + b_ih[k];
    float xz = w_ih[(size_t)(k + 256) * VOCAB + c] + b_ih[k + 256];
    float xn = w_ih[(size_t)(k + 512) * VOCAB + c] + b_ih[k + 512];

    float hr = hproj[b * GH + k]       + b_hh[k];
    float hz = hproj[b * GH + 256 + k] + b_hh[k + 256];
    float hn = hproj[b * GH + 512 + k] + b_hh[k + 512];

    float rg = fast_sigmoid(xr + hr);
    float zg = fast_sigmoid(xz + hz);
    float ng = fast_tanh(xn + rg * hn);
    float h0 = hidden[b * HID + k];
    float h1 = (1.0f - zg) * ng + zg * h0;

    h1out[b * HID + k] = h1;

    // fragment-ordered bf16 write
    int mt = b >> 4, rr = b & 15;
    int kk = k >> 5, gg = (k >> 3) & 3, e = k & 7;
    size_t fid = (size_t)((mt * 8 + kk) * 4 + gg) * 16 + rr;
    h1frag[fid * 8 + e] = f2bf(h1);
}

extern "C" void kernel_launch(void* const* d_in, const int* in_sizes, int n_in,
                              void* d_out, int out_size, void* d_ws, size_t ws_size,
                              hipStream_t stream) {
    const int*   input  = (const int*)  d_in[0];
    // d_in[1] = target (unused)
    const float* hidden = (const float*)d_in[2];
    const float* w_ih   = (const float*)d_in[3];
    const float* w_hh   = (const float*)d_in[4];
    const float* b_ih   = (const float*)d_in[5];
    const float* b_hh   = (const float*)d_in[6];
    const float* w_out  = (const float*)d_in[7];
    const float* b_out  = (const float*)d_in[8];

    float* logit = (float*)d_out;                            // [512, 50000]
    float* h1    = (float*)d_out + (size_t)BATCH * VOCAB;    // [512, 256]

    u32x4* hfrag  = (u32x4*)d_ws;                                  // 256 KB
    u32x4* h1frag = (u32x4*)((char*)d_ws + 256 * 1024);            // 256 KB
    float* hproj  = (float*)((char*)d_ws + 512 * 1024);           // 1.5 MB

    const int nFrag = BATCH * HID / 8;   // 16384

    // K0: hidden -> fragment-ordered bf16
    repack_f32<<<nFrag / 256, 256, 0, stream>>>(hidden, hfrag, nFrag);

    // K1: hproj = h0 @ w_hh^T   (512 x 768, K=256)
    dim3 g1(GH / 64, BATCH / 64);           // (12, 8) = 96 blocks, mChunks = 1
    gemm_ms<0><<<g1, 256, 0, stream>>>(hfrag, w_hh, hproj, nullptr, GH, 1);

    // K2: gates -> h1 (f32) + h1frag (fragment-ordered bf16)
    gru_gate<<<BATCH, 256, 0, stream>>>(input, hidden, w_ih, b_ih, b_hh, hproj,
                                        h1, (unsigned short*)h1frag);

    // K3: logit = tanh(h1 @ w_out^T + b_out)   (512 x 50000, K=256)
    dim3 g3((VOCAB + 63) / 64, 1);          // 782 blocks, mChunks = 8
    gemm_ms<1><<<g3, 256, 0, stream>>>(h1frag, w_out, logit, b_out, VOCAB, 8);
}